// Round 7
// baseline (13.728 us; speedup 1.0000x reference)
//
#include <hip/hip_runtime.h>

// BagOfWords: out[b][v] = count of token v in docs[b][:] / SEQ
// docs: int32 [256, 2048], out: float32 [256, 32000]
//
// R7 = R6 with the nontemporal stores fixed to use a native clang vector
// type (ext_vector_type(4)) — __builtin_nontemporal_store rejects HIP's
// struct-wrapped float4.
//
// Structure: exact R4 (4 vocab chunks x 512 threads, 1024 blocks ->
// 4 blocks/CU, 32 waves/CU; loads issued AFTER the zero barrier — every
// hoisted variant regressed: R2/R3/R5) plus two single-phase tweaks:
//  + u16-packed LDS bins (counts <= 2048 < 65536, exact): zero phase
//    4->2 iters, readback 4->2 ds_read_b128.   [16 KB LDS/block]
//  + nontemporal output stores: 32.8 MB stream is never re-read; skip
//    L2 write-allocate churn.

#define VOCAB 32000
#define BATCH 256
#define SEQ   2048
#define NCHUNK 4
#define CHUNK (VOCAB / NCHUNK)   // 8000 bins -> 4000 packed u32 = 16 KB LDS
#define BLK   512

typedef float f32x4 __attribute__((ext_vector_type(4)));

__global__ __launch_bounds__(BLK) void bow_hist_kernel(
    const int* __restrict__ docs, float* __restrict__ out) {
    __shared__ unsigned int binsP[CHUNK / 2];   // 2 u16 counters per u32

    const int wg   = blockIdx.x;          // natural mapping (R4-proven)
    const int b    = wg >> 2;             // row index
    const int c    = wg & (NCHUNK - 1);   // vocab chunk
    const int base = c * CHUNK;
    const int tid  = threadIdx.x;

    // 1) zero the packed histogram (1000 uint4 -> 2 iters/thread)
    uint4* binsP4 = reinterpret_cast<uint4*>(binsP);
    for (int i = tid; i < CHUNK / 8; i += BLK) {
        binsP4[i] = make_uint4(0u, 0u, 0u, 0u);
    }
    __syncthreads();

    // 2) scan the row: 512 int4 covers all 2048 tokens (1 per thread).
    //    Packed u16 atomics: bin r -> word r>>1, half r&1; counts <= 2048
    //    so no carry into the neighbor halfword.
    const int4* row4 = reinterpret_cast<const int4*>(docs + (size_t)b * SEQ);
    int4 t = row4[tid];
    int r;
    r = t.x - base;
    if ((unsigned)r < (unsigned)CHUNK)
        atomicAdd(&binsP[r >> 1], (r & 1) ? 0x10000u : 1u);
    r = t.y - base;
    if ((unsigned)r < (unsigned)CHUNK)
        atomicAdd(&binsP[r >> 1], (r & 1) ? 0x10000u : 1u);
    r = t.z - base;
    if ((unsigned)r < (unsigned)CHUNK)
        atomicAdd(&binsP[r >> 1], (r & 1) ? 0x10000u : 1u);
    r = t.w - base;
    if ((unsigned)r < (unsigned)CHUNK)
        atomicAdd(&binsP[r >> 1], (r & 1) ? 0x10000u : 1u);
    __syncthreads();

    // 3) stream the chunk out, normalized; one ds_read_b128 yields 8 bins
    //    -> two nontemporal 16B stores.
    float* orow = out + (size_t)b * VOCAB + base;
    const float inv = 1.0f / (float)SEQ;   // exact power of two
    for (int i = tid; i < CHUNK / 8; i += BLK) {   // 2 iters/thread
        uint4 u = binsP4[i];
        f32x4 v0, v1;
        v0.x = (float)(u.x & 0xFFFFu) * inv;
        v0.y = (float)(u.x >> 16)     * inv;
        v0.z = (float)(u.y & 0xFFFFu) * inv;
        v0.w = (float)(u.y >> 16)     * inv;
        v1.x = (float)(u.z & 0xFFFFu) * inv;
        v1.y = (float)(u.z >> 16)     * inv;
        v1.z = (float)(u.w & 0xFFFFu) * inv;
        v1.w = (float)(u.w >> 16)     * inv;
        f32x4* dst = reinterpret_cast<f32x4*>(orow) + i * 2;
        __builtin_nontemporal_store(v0, dst + 0);
        __builtin_nontemporal_store(v1, dst + 1);
    }
}

extern "C" void kernel_launch(void* const* d_in, const int* in_sizes, int n_in,
                              void* d_out, int out_size, void* d_ws, size_t ws_size,
                              hipStream_t stream) {
    const int* docs = (const int*)d_in[0];
    float* out = (float*)d_out;
    bow_hist_kernel<<<dim3(BATCH * NCHUNK), dim3(BLK), 0, stream>>>(docs, out);
}

// Round 8
// 11.299 us; speedup vs baseline: 1.2149x; 1.2149x over previous
//
#include <hip/hip_runtime.h>

// BagOfWords: out[b][v] = count of token v in docs[b][:] / SEQ
// docs: int32 [256, 2048], out: float32 [256, 32000]
//
// R8 = exact R4 structure (the 11.8 us best: 4 vocab chunks x 512 threads,
// 1024 blocks -> 4 blocks/CU, 32 waves/CU; u32 LDS bins; loads issued
// AFTER the zero barrier; natural block ids; lane-consecutive float4
// stores) + ONE change: nontemporal output stores (output never re-read;
// skip L2 write-allocate churn that evicts docs rows).
//
// Journal: R2/R3/R5 hoisted loads -> regress. R5/R7 u16-packed bins ->
// regress (strided store pattern breaks write coalescing + packed-word
// atomic collisions). Single-variable discipline from here.

#define VOCAB 32000
#define BATCH 256
#define SEQ   2048
#define NCHUNK 4
#define CHUNK (VOCAB / NCHUNK)   // 8000 bins -> 32 KB LDS
#define BLK   512

typedef float f32x4 __attribute__((ext_vector_type(4)));

__global__ __launch_bounds__(BLK) void bow_hist_kernel(
    const int* __restrict__ docs, float* __restrict__ out) {
    __shared__ unsigned int bins[CHUNK];

    const int wg   = blockIdx.x;          // natural mapping (R4-proven)
    const int b    = wg >> 2;             // row index
    const int c    = wg & (NCHUNK - 1);   // vocab chunk
    const int base = c * CHUNK;
    const int tid  = threadIdx.x;

    // 1) zero the LDS histogram chunk (ds_write_b128; 2000 uint4)
    uint4* bins4 = reinterpret_cast<uint4*>(bins);
    for (int i = tid; i < CHUNK / 4; i += BLK) {   // ~4 iters
        bins4[i] = make_uint4(0u, 0u, 0u, 0u);
    }
    __syncthreads();

    // 2) scan the row: 512 int4 covers all 2048 tokens (1 per thread)
    const int4* row4 = reinterpret_cast<const int4*>(docs + (size_t)b * SEQ);
    int4 t = row4[tid];
    int r;
    r = t.x - base; if ((unsigned)r < (unsigned)CHUNK) atomicAdd(&bins[r], 1u);
    r = t.y - base; if ((unsigned)r < (unsigned)CHUNK) atomicAdd(&bins[r], 1u);
    r = t.z - base; if ((unsigned)r < (unsigned)CHUNK) atomicAdd(&bins[r], 1u);
    r = t.w - base; if ((unsigned)r < (unsigned)CHUNK) atomicAdd(&bins[r], 1u);
    __syncthreads();

    // 3) stream the chunk out, normalized; lane-consecutive float4 stores
    //    (perfectly coalesced), nontemporal.
    float* orow = out + (size_t)b * VOCAB + base;
    const float inv = 1.0f / (float)SEQ;   // exact power of two
    for (int i = tid; i < CHUNK / 4; i += BLK) {   // ~4 iters
        uint4 u = bins4[i];
        f32x4 v;
        v.x = (float)u.x * inv;
        v.y = (float)u.y * inv;
        v.z = (float)u.z * inv;
        v.w = (float)u.w * inv;
        __builtin_nontemporal_store(v, reinterpret_cast<f32x4*>(orow) + i);
    }
}

extern "C" void kernel_launch(void* const* d_in, const int* in_sizes, int n_in,
                              void* d_out, int out_size, void* d_ws, size_t ws_size,
                              hipStream_t stream) {
    const int* docs = (const int*)d_in[0];
    float* out = (float*)d_out;
    bow_hist_kernel<<<dim3(BATCH * NCHUNK), dim3(BLK), 0, stream>>>(docs, out);
}